// Round 5
// baseline (135.833 us; speedup 1.0000x reference)
//
#include <hip/hip_runtime.h>
#include <cstdint>

constexpr int Bv = 16, Nv = 4096, Fv = 512, Sv = 8, Kv = 1024, Dv = 64;
constexpr int Mv = Bv * Nv;  // 65536 rows
#define BDIM 256
constexpr int RG = 8;        // 16-row groups per wave
constexpr int RPW = RG * 16; // 128 rows per wave
constexpr int RPB = 4 * RPW; // 512 rows per block

using bf16x8 = __attribute__((ext_vector_type(8))) short;
using f32x4  = __attribute__((ext_vector_type(4))) float;
typedef unsigned short u16;
typedef unsigned int u32;

__device__ __forceinline__ u16 bf16rne(float f) {
  union { float f; u32 u; } v; v.f = f;
  u32 u = v.u + 0x7FFFu + ((v.u >> 16) & 1u);
  return (u16)(u >> 16);
}

__device__ __forceinline__ void gload_lds16(const void* g, void* lds) {
  __builtin_amdgcn_global_load_lds(
      (const __attribute__((address_space(1))) void*)g,
      (__attribute__((address_space(3))) void*)lds, 16, 0, 0);
}

// prep: cb fp32 -> (a) swizzled bf16 codebook, (b) c2m = -0.5*sum(c^2) (argmax form)
// swz layout: [s*1024+cw][slot'][8 bf16], slot' = slot ^ (cw&7)
__global__ void prep_kernel(const float* __restrict__ cb, u16* __restrict__ swz,
                            float* __restrict__ c2m) {
  int idx = blockIdx.x * BDIM + threadIdx.x;  // s*1024+cw
  int cw = idx & (Kv - 1);
  const float4* src = (const float4*)(cb + (size_t)idx * Dv);
  float v[64];
  float s2 = 0.f;
#pragma unroll
  for (int i = 0; i < 16; ++i) {
    float4 f = src[i];
    v[i * 4 + 0] = f.x; v[i * 4 + 1] = f.y; v[i * 4 + 2] = f.z; v[i * 4 + 3] = f.w;
    s2 += f.x * f.x + f.y * f.y + f.z * f.z + f.w * f.w;
  }
  c2m[idx] = -0.5f * s2;
  uint4* out = (uint4*)(swz + (size_t)idx * Dv);
#pragma unroll
  for (int slot = 0; slot < 8; ++slot) {
    int slotp = slot ^ (cw & 7);
    u32 w[4];
#pragma unroll
    for (int p = 0; p < 4; ++p)
      w[p] = (u32)bf16rne(v[slot * 8 + p * 2]) | ((u32)bf16rne(v[slot * 8 + p * 2 + 1]) << 16);
    uint4 pk; pk.x = w[0]; pk.y = w[1]; pk.z = w[2]; pk.w = w[3];
    out[slotp] = pk;
  }
}

// main: block = 512 rows x 1 subspace; wave = 128 rows x all 1024 codewords.
// score = <x,c> - 0.5*c2 via mfma(A=cb, B=x, C=c2m). Lane-local argMAX with the
// codeword index OR'd into the score's low-10 mantissa bits (v_or3 + v_max):
// perturbation <= 1023 ulp (~1e-7 abs at |score|~0.005), covered by the 2/K
// quant bound. Distance-2 prefetch pipeline, counted vmcnt, raw barriers.
__global__ __launch_bounds__(BDIM, 4) void pq_mfma(
    const float* __restrict__ x, const float* __restrict__ cb,
    const u16* __restrict__ swz, const float* __restrict__ c2m_g,
    float* __restrict__ quant, float* __restrict__ devpart) {
  __shared__ __attribute__((aligned(16))) u16 cbuf[4][64 * Dv];  // 4 x 8KB
  __shared__ __attribute__((aligned(16))) float c2_lds[Kv];      // 4KB

  const int tid = threadIdx.x;
  const int s = blockIdx.y;
  const int row0 = blockIdx.x * RPB;
  const int wave = tid >> 6, lane = tid & 63;
  const int l15 = lane & 15, lg = lane >> 4;
  const int slotp0 = lg ^ (lane & 7);        // h=0 slot (cw&7 == l15&7 == lane&7)
  const int slotp1 = (4 + lg) ^ (lane & 7);  // h=1 slot
  const u32 lg4 = (u32)(lg * 4);

  // ---- prologue staging: c2 (1 gload/wave) + chunks 0,1 (2 gloads/wave each)
  gload_lds16(c2m_g + s * Kv + tid * 4, &c2_lds[(tid & ~63) * 4]);
  const u16* swz_s = swz + (size_t)s * Kv * Dv;
  auto stage = [&](int cc, int slot) {  // slot must be a compile-time constant
    const u16* srcb = swz_s + (size_t)cc * 64 * Dv;
    u16* dstb = &cbuf[slot][0];
#pragma unroll
    for (int it = 0; it < 2; ++it)
      gload_lds16(srcb + (size_t)(it * BDIM + tid) * 8,
                  dstb + (it * BDIM + (tid & ~63)) * 8);
  };
  stage(0, 0); stage(1, 1);

  // ---- x rows -> bf16 fragments + fp32 x2 partials (overlaps staging flight)
  bf16x8 xf[RG][2];
  float x2p[RG];
#pragma unroll
  for (int rg = 0; rg < RG; ++rg) {
    x2p[rg] = 0.f;
    const int row = row0 + wave * RPW + rg * 16 + l15;
    const float* xp = x + (size_t)row * Fv + s * Dv + lg * 8;
#pragma unroll
    for (int h = 0; h < 2; ++h) {
      float4 f0 = *(const float4*)(xp + h * 32);
      float4 f1 = *(const float4*)(xp + h * 32 + 4);
      x2p[rg] += f0.x * f0.x + f0.y * f0.y + f0.z * f0.z + f0.w * f0.w
               + f1.x * f1.x + f1.y * f1.y + f1.z * f1.z + f1.w * f1.w;
      bf16x8 v;
      v[0] = (short)bf16rne(f0.x); v[1] = (short)bf16rne(f0.y);
      v[2] = (short)bf16rne(f0.z); v[3] = (short)bf16rne(f0.w);
      v[4] = (short)bf16rne(f1.x); v[5] = (short)bf16rne(f1.y);
      v[6] = (short)bf16rne(f1.z); v[7] = (short)bf16rne(f1.w);
      xf[rg][h] = v;
    }
  }

  float bv[RG];
#pragma unroll
  for (int rg = 0; rg < RG; ++rg) bv[rg] = -3.0e38f;

  // all-but-2-newest drained => my c2+chunk0 slices landed; barrier makes it global
  asm volatile("s_waitcnt vmcnt(2)" ::: "memory");
  __builtin_amdgcn_s_barrier();

  auto chunk = [&](int cc, int bufi) {  // bufi compile-time
    const u16* cbb = &cbuf[bufi][0];
    const int kb0 = cc * 64;
#pragma unroll
    for (int ct = 0; ct < 4; ++ct) {
      f32x4 c2v = *(const f32x4*)&c2_lds[kb0 + ct * 16 + lg * 4];
      const u16* ap = &cbb[(ct * 16 + l15) * Dv];
      bf16x8 a0 = *(const bf16x8*)&ap[slotp0 * 8];
      bf16x8 a1 = *(const bf16x8*)&ap[slotp1 * 8];
      const u32 kbase = (u32)(kb0 + ct * 16);
#pragma unroll
      for (int rg = 0; rg < RG; ++rg) {
        f32x4 acc = __builtin_amdgcn_mfma_f32_16x16x32_bf16(a0, xf[rg][0], c2v, 0, 0, 0);
        acc = __builtin_amdgcn_mfma_f32_16x16x32_bf16(a1, xf[rg][1], acc, 0, 0, 0);
#pragma unroll
        for (int r = 0; r < 4; ++r) {
          u32 pk = (__builtin_bit_cast(u32, acc[r]) | lg4) | (kbase + (u32)r);
          bv[rg] = fmaxf(bv[rg], __builtin_bit_cast(float, pk));
        }
      }
    }
  };

  // ---- main loop: chunks 0..11, stage distance 2; vmcnt(2) BEFORE barrier so
  // every wave's next-chunk slice is proven landed before any wave is released
  for (int c = 0; c < 12; c += 4) {
#pragma unroll
    for (int p = 0; p < 4; ++p) {
      stage(c + p + 2, (p + 2) & 3);
      chunk(c + p, p);
      asm volatile("s_waitcnt vmcnt(2) lgkmcnt(0)" ::: "memory");
      __builtin_amdgcn_s_barrier();
    }
  }
  // ---- peeled tail: 12..15
  stage(14, 2); chunk(12, 0);
  asm volatile("s_waitcnt vmcnt(2) lgkmcnt(0)" ::: "memory");
  __builtin_amdgcn_s_barrier();
  stage(15, 3); chunk(13, 1);
  asm volatile("s_waitcnt vmcnt(2) lgkmcnt(0)" ::: "memory");
  __builtin_amdgcn_s_barrier();
  chunk(14, 2);
  asm volatile("s_waitcnt vmcnt(0) lgkmcnt(0)" ::: "memory");
  __builtin_amdgcn_s_barrier();
  chunk(15, 3);

  // ---- cross-lane: max of packed scores + sum of x2 over the 4 lg groups
#pragma unroll
  for (int rg = 0; rg < RG; ++rg) {
    float b = bv[rg], xx = x2p[rg];
    b = fmaxf(b, __shfl_xor(b, 16, 64)); xx += __shfl_xor(xx, 16, 64);
    b = fmaxf(b, __shfl_xor(b, 32, 64)); xx += __shfl_xor(xx, 32, 64);
    bv[rg] = b; x2p[rg] = xx;
  }

  // dev partial: dist_row = x2 - 2*score_max (packed low bits ~1e-7, negligible)
  float dev = 0.f;
#pragma unroll
  for (int rg = 0; rg < RG; ++rg) dev += x2p[rg] - 2.f * bv[rg];
#pragma unroll
  for (int m = 1; m <= 8; m <<= 1) dev += __shfl_xor(dev, m, 64);
  if (lane == 0)
    devpart[((size_t)blockIdx.y * gridDim.x + blockIdx.x) * 4 + wave] = dev;

  // ---- coalesced quant gather: iter i covers rows i*4+lg; index via shfl from
  // the lane holding that row (l15 = 4*(i&3)+lg), k = low 10 bits of packed max
  const float* cbs = cb + (size_t)s * Kv * Dv;
  float* qbase = quant + (size_t)(row0 + wave * RPW) * Fv + s * Dv;
#pragma unroll
  for (int i = 0; i < 32; ++i) {
    int rl = i * 4 + lg;
    int kk = __shfl(__builtin_bit_cast(int, bv[i >> 2]), 4 * (i & 3) + lg, 64) & 1023;
    float4 v = *(const float4*)(cbs + (size_t)kk * Dv + l15 * 4);
    *(float4*)(qbase + (size_t)rl * Fv + l15 * 4) = v;
  }
}

// deterministic final reduction of 4096 wave partials -> dev scalar
__global__ void dev_reduce(const float* __restrict__ part, float* __restrict__ out) {
  __shared__ float sred[256];
  int tid = threadIdx.x;
  float s = 0.f;
  for (int i = tid; i < 4096; i += 256) s += part[i];
  sred[tid] = s;
  __syncthreads();
  for (int off = 128; off > 0; off >>= 1) {
    if (tid < off) sred[tid] += sred[tid + off];
    __syncthreads();
  }
  if (tid == 0) out[0] = sred[0] * (1.25f / 4194304.0f);
}

extern "C" void kernel_launch(void* const* d_in, const int* in_sizes, int n_in,
                              void* d_out, int out_size, void* d_ws, size_t ws_size,
                              hipStream_t stream) {
  const float* x = (const float*)d_in[0];   // (B,N,F) fp32
  const float* cb = (const float*)d_in[1];  // (S,K,D) fp32
  float* quant = (float*)d_out;
  float* dev = quant + (size_t)Mv * Fv;

  // ws: swz bf16 codebook (1MB), c2m (32KB), dev partials (16KB)
  u16* swz = (u16*)d_ws;
  float* c2m = (float*)(swz + (size_t)Sv * Kv * Dv);
  float* part = c2m + Sv * Kv;

  prep_kernel<<<(Sv * Kv) / BDIM, BDIM, 0, stream>>>(cb, swz, c2m);
  dim3 grid(Mv / RPB, Sv);
  pq_mfma<<<grid, BDIM, 0, stream>>>(x, cb, swz, c2m, quant, part);
  dev_reduce<<<1, 256, 0, stream>>>(part, dev);
}